// Round 9
// baseline (243.061 us; speedup 1.0000x reference)
//
#include <hip/hip_runtime.h>
#include <hip/hip_bf16.h>

#define D_MODEL 1024
#define N_HEADS 16
#define HEAD_DIM 64
#define SEQ 2048
#define BATCH 2

typedef __attribute__((ext_vector_type(8))) short bf16x8;
typedef __attribute__((ext_vector_type(4))) float f32x4;

typedef __attribute__((address_space(3))) unsigned lds_uint;
typedef __attribute__((address_space(1))) const unsigned global_cuint;

__device__ __forceinline__ void async_cp16(const ushort* g, ushort* l) {
  __builtin_amdgcn_global_load_lds((global_cuint*)g, (lds_uint*)l, 16, 0, 0);
}

__device__ __forceinline__ ushort f2b(float f) {
  union { float f; unsigned u; } x; x.f = f;
  unsigned r = x.u + 0x7fffu + ((x.u >> 16) & 1u);
  return (ushort)(r >> 16);
}

// packed f32x2 -> bf16x2; low word = a
__device__ __forceinline__ unsigned pk2(float a, float b) {
  __hip_bfloat162 h = __float22bfloat162_rn(float2{a, b});
  union { __hip_bfloat162 h; unsigned u; } x; x.h = h;
  return x.u;
}

__device__ __forceinline__ float blo(unsigned u) {
  union { unsigned u; float f; } x; x.u = u << 16; return x.f;
}
__device__ __forceinline__ float bhi(unsigned u) {
  union { unsigned u; float f; } x; x.u = u & 0xffff0000u; return x.f;
}

// Single fused cast: x (1M uint4) + Wq/Wk/Wv (-> wqkv) + Wo (-> wob).
__global__ __launch_bounds__(256) void cast_all(const float* __restrict__ x,
                                                const float* __restrict__ Wq,
                                                const float* __restrict__ Wk,
                                                const float* __restrict__ Wv,
                                                const float* __restrict__ Wo,
                                                ushort* __restrict__ xb,
                                                ushort* __restrict__ wqkv,
                                                ushort* __restrict__ wob) {
  int idx = blockIdx.x * 256 + threadIdx.x;  // 0 .. 2M-1 (uint4 units)
  const float* in;
  uint2* out;
  if (idx < (1 << 20)) {
    in = x; out = (uint2*)xb;
  } else {
    int j = idx - (1 << 20);
    int w = j >> 18;            // 0..3
    idx = j & 0x3FFFF;          // 256K uint4 per weight
    switch (w) {
      case 0: in = Wq; out = (uint2*)wqkv; break;
      case 1: in = Wk; out = (uint2*)(wqkv) + (1 << 18); break;
      case 2: in = Wv; out = (uint2*)(wqkv) + (2 << 18); break;
      default: in = Wo; out = (uint2*)wob; break;
    }
  }
  float4 v = ((const float4*)in)[idx];
  uint2 o; o.x = pk2(v.x, v.y); o.y = pk2(v.z, v.w);
  out[idx] = o;
}

// Fused QKV projection: A = xb (4096x1024 bf16), Bw = wqkv (3072x1024 bf16).
// 128x128 tile, BK=64 (16 K-iters).
// n<1024 -> Q (scaled), <2048 -> K, else -> V^T (packed b64 stores along t).
__global__ __launch_bounds__(256) void gemm_qkv(const ushort* __restrict__ A,
                                                const ushort* __restrict__ Bw,
                                                ushort* __restrict__ Qh,
                                                ushort* __restrict__ Kh,
                                                ushort* __restrict__ Vth,
                                                float qscale) {
  constexpr int K = 1024;
  const int bm = blockIdx.y * 128;
  const int bn = blockIdx.x * 128;
  const int tid = threadIdx.x;
  const int wave = tid >> 6;
  const int lane = tid & 63;
  const int l16 = lane & 15;
  const int quad = lane >> 4;

  __shared__ ushort As[128 * 64];   // 16 KB
  __shared__ ushort Bs[128 * 64];   // 16 KB

  const int wm = (wave & 1) * 64;
  const int wn = (wave >> 1) * 64;

  f32x4 acc[4][4];
#pragma unroll
  for (int r = 0; r < 4; ++r)
#pragma unroll
    for (int c = 0; c < 4; ++c) acc[r][c] = (f32x4){0.f, 0.f, 0.f, 0.f};

  const int srow = wave * 8 + (lane >> 3);
  const int scol = (lane & 7) * 8;

  for (int k0 = 0; k0 < K; k0 += 64) {
#pragma unroll
    for (int j = 0; j < 4; ++j) {
      async_cp16(A  + (size_t)(bm + j * 32 + srow) * K + k0 + scol, &As[(j * 32 + wave * 8) * 64]);
      async_cp16(Bw + (size_t)(bn + j * 32 + srow) * K + k0 + scol, &Bs[(j * 32 + wave * 8) * 64]);
    }
    __syncthreads();

    bf16x8 a[2][4], b[2][4];
#pragma unroll
    for (int ks = 0; ks < 2; ++ks)
#pragma unroll
      for (int r = 0; r < 4; ++r) {
        a[ks][r] = *(const bf16x8*)(&As[(wm + r * 16 + l16) * 64 + ks * 32 + quad * 8]);
        b[ks][r] = *(const bf16x8*)(&Bs[(wn + r * 16 + l16) * 64 + ks * 32 + quad * 8]);
      }
#pragma unroll
    for (int ks = 0; ks < 2; ++ks)
#pragma unroll
      for (int r = 0; r < 4; ++r)
#pragma unroll
        for (int c = 0; c < 4; ++c)
          acc[r][c] = __builtin_amdgcn_mfma_f32_16x16x32_bf16(a[ks][r], b[ks][c], acc[r][c], 0, 0, 0);
    __syncthreads();
  }

#pragma unroll
  for (int r = 0; r < 4; ++r) {
#pragma unroll
    for (int c = 0; c < 4; ++c) {
      int ncol = bn + wn + c * 16 + l16;   // 0..3071; w uniform per (block,wave)
      int w = ncol >> 10;
      int f = ncol & 1023;
      int h = f >> 6, d = f & 63;
      if (w == 2) {
        // V^T: 4 consecutive tokens per lane -> one b64 store
        int m0 = bm + wm + r * 16 + quad * 4;
        int b = m0 >> 11, t0 = m0 & 2047;
        uint2 pp;
        pp.x = pk2(acc[r][c][0], acc[r][c][1]);
        pp.y = pk2(acc[r][c][2], acc[r][c][3]);
        *(uint2*)(&Vth[((size_t)(b * 1024 + f) << 11) + t0]) = pp;
      } else {
#pragma unroll
        for (int rr = 0; rr < 4; ++rr) {
          float v = acc[r][c][rr];
          int m = bm + wm + r * 16 + quad * 4 + rr;
          int b = m >> 11, t = m & 2047;
          if (w == 0)
            Qh[((size_t)(b * 16 + h) * SEQ + t) * 64 + d] = f2b(v * qscale);
          else
            Kh[((size_t)(b * 16 + h) * SEQ + t) * 64 + d] = f2b(v);
        }
      }
    }
  }
}

// Output projection: A = ctx (4096x1024 bf16), Bw = wob, fp32 out.
// 64x128 tile, BK=64.
__global__ __launch_bounds__(256) void gemm_out(const ushort* __restrict__ A,
                                                const ushort* __restrict__ Bw,
                                                float* __restrict__ out) {
  constexpr int K = 1024;
  const int bm = blockIdx.y * 64;
  const int bn = blockIdx.x * 128;
  const int tid = threadIdx.x;
  const int wave = tid >> 6;
  const int lane = tid & 63;
  const int l16 = lane & 15;
  const int quad = lane >> 4;

  __shared__ ushort As[64 * 64];    //  8 KB
  __shared__ ushort Bs[128 * 64];   // 16 KB

  const int wm = (wave & 1) * 32;
  const int wn = (wave >> 1) * 64;

  f32x4 acc[2][4];
#pragma unroll
  for (int r = 0; r < 2; ++r)
#pragma unroll
    for (int c = 0; c < 4; ++c) acc[r][c] = (f32x4){0.f, 0.f, 0.f, 0.f};

  const int srow = wave * 8 + (lane >> 3);
  const int scol = (lane & 7) * 8;

  for (int k0 = 0; k0 < K; k0 += 64) {
#pragma unroll
    for (int j = 0; j < 2; ++j)
      async_cp16(A + (size_t)(bm + j * 32 + srow) * K + k0 + scol, &As[(j * 32 + wave * 8) * 64]);
#pragma unroll
    for (int j = 0; j < 4; ++j)
      async_cp16(Bw + (size_t)(bn + j * 32 + srow) * K + k0 + scol, &Bs[(j * 32 + wave * 8) * 64]);
    __syncthreads();

    bf16x8 a[2][2], b[2][4];
#pragma unroll
    for (int ks = 0; ks < 2; ++ks) {
#pragma unroll
      for (int r = 0; r < 2; ++r)
        a[ks][r] = *(const bf16x8*)(&As[(wm + r * 16 + l16) * 64 + ks * 32 + quad * 8]);
#pragma unroll
      for (int c = 0; c < 4; ++c)
        b[ks][c] = *(const bf16x8*)(&Bs[(wn + c * 16 + l16) * 64 + ks * 32 + quad * 8]);
    }
#pragma unroll
    for (int ks = 0; ks < 2; ++ks)
#pragma unroll
      for (int r = 0; r < 2; ++r)
#pragma unroll
        for (int c = 0; c < 4; ++c)
          acc[r][c] = __builtin_amdgcn_mfma_f32_16x16x32_bf16(a[ks][r], b[ks][c], acc[r][c], 0, 0, 0);
    __syncthreads();
  }

#pragma unroll
  for (int r = 0; r < 2; ++r)
#pragma unroll
    for (int c = 0; c < 4; ++c)
#pragma unroll
      for (int rr = 0; rr < 4; ++rr) {
        int m = bm + wm + r * 16 + quad * 4 + rr;
        int n = bn + wn + c * 16 + l16;
        out[(size_t)m * D_MODEL + n] = acc[r][c][rr];
      }
}

// Flash attention: S^T formulation, fixed-max softmax (exp2 domain), split-K=2.
// R9: 32 q-rows per wave (2 groups), q-tile 128/block -> grid 1024 blocks =
// 4 blocks/CU = 16 waves/CU (2x R8 TLP; the kernel was latency-bound with
// every pipe <27%). Pt = per-wave rotating 16-row buffer (R6-proven safe:
// same-wave LDS ops are in-order). LDS 27.6 KB.
__global__ __launch_bounds__(256, 4) void attn_kernel(const ushort* __restrict__ Qh,
                                                      const ushort* __restrict__ Kh,
                                                      const ushort* __restrict__ Vth,
                                                      ushort* __restrict__ O1,
                                                      ushort* __restrict__ O2,
                                                      float* __restrict__ l1,
                                                      float* __restrict__ l2) {
  const int bh = blockIdx.y;
  const int q0 = blockIdx.x * 128;
  const int half = blockIdx.z;
  ushort* __restrict__ Op = half ? O2 : O1;
  float* __restrict__ lp = half ? l2 : l1;

  const int tid = threadIdx.x;
  const int wave = tid >> 6;
  const int lane = tid & 63;
  const int l16 = lane & 15;
  const int quad = lane >> 4;

  __shared__ ushort Kt[64 * 72];      // [key][d]
  __shared__ ushort Vt[64 * 72];      // [d][key]
  __shared__ ushort Pt[4 * 16 * 72];  // per-wave 16 q-rows, rotated across g

  bf16x8 qf[2][2];
#pragma unroll
  for (int g = 0; g < 2; ++g) {
    const ushort* qp = Qh + ((size_t)bh * SEQ + q0 + wave * 32 + g * 16 + l16) * 64 + quad * 8;
    qf[g][0] = *(const bf16x8*)(qp);
    qf[g][1] = *(const bf16x8*)(qp + 32);
  }

  bf16x8 ones;
#pragma unroll
  for (int j = 0; j < 8; ++j) ones[j] = (short)0x3F80;  // bf16 1.0

  f32x4 o[2][4];
  f32x4 lacc[2];
#pragma unroll
  for (int g = 0; g < 2; ++g) {
    lacc[g] = (f32x4){0.f, 0.f, 0.f, 0.f};
#pragma unroll
    for (int c = 0; c < 4; ++c) o[g][c] = (f32x4){0.f, 0.f, 0.f, 0.f};
  }

  const int srow = tid >> 3;        // 0..31
  const int scol = (tid & 7) * 8;
  const ushort* kbase = Kh + ((size_t)bh * SEQ + half * 1024) * 64;
  const ushort* vbase = Vth + (size_t)bh * 64 * SEQ + half * 1024;

  uint4 kreg[2], vreg[2];
#pragma unroll
  for (int i = 0; i < 2; ++i) {
    kreg[i] = *(const uint4*)(kbase + (size_t)(i * 32 + srow) * 64 + scol);
    vreg[i] = *(const uint4*)(vbase + (size_t)(i * 32 + srow) * SEQ + scol);
  }

  const int pbase = wave * 1152;    // 16 rows * 72
  constexpr int NIT = 1024 / 64;    // 16
  for (int kt = 0; kt < NIT; ++kt) {
    __syncthreads();  // prior-iter LDS reads complete
#pragma unroll
    for (int i = 0; i < 2; ++i) {
      *(uint4*)(&Kt[(i * 32 + srow) * 72 + scol]) = kreg[i];
      *(uint4*)(&Vt[(i * 32 + srow) * 72 + scol]) = vreg[i];
    }
    __syncthreads();  // staging visible
    if (kt + 1 < NIT) {
      // issued after the barrier so its vmcnt drain doesn't eat the prefetch
#pragma unroll
      for (int i = 0; i < 2; ++i) {
        kreg[i] = *(const uint4*)(kbase + (size_t)((kt + 1) * 64 + i * 32 + srow) * 64 + scol);
        vreg[i] = *(const uint4*)(vbase + (size_t)(i * 32 + srow) * SEQ + (kt + 1) * 64 + scol);
      }
    }

    // hoisted K frags (A-op: m = key c*16+l16, k = d) and V frags (B-op: n = d)
    bf16x8 ka[4][2], vb[4][2];
#pragma unroll
    for (int c = 0; c < 4; ++c)
#pragma unroll
      for (int ks = 0; ks < 2; ++ks) {
        ka[c][ks] = *(const bf16x8*)(&Kt[(c * 16 + l16) * 72 + ks * 32 + quad * 8]);
        vb[c][ks] = *(const bf16x8*)(&Vt[(c * 16 + l16) * 72 + ks * 32 + quad * 8]);
      }

#pragma unroll
    for (int g = 0; g < 2; ++g) {
      const int prow = pbase + l16 * 72;
      // S^T per key-chunk: MFMA -> exp2 -> pack -> LDS (no cross-lane ops)
#pragma unroll
      for (int c = 0; c < 4; ++c) {
        f32x4 z = (f32x4){0.f, 0.f, 0.f, 0.f};
        z = __builtin_amdgcn_mfma_f32_16x16x32_bf16(ka[c][0], qf[g][0], z, 0, 0, 0);
        z = __builtin_amdgcn_mfma_f32_16x16x32_bf16(ka[c][1], qf[g][1], z, 0, 0, 0);
        uint2 pp;
        pp.x = pk2(__builtin_amdgcn_exp2f(z[0]), __builtin_amdgcn_exp2f(z[1]));
        pp.y = pk2(__builtin_amdgcn_exp2f(z[2]), __builtin_amdgcn_exp2f(z[3]));
        *(uint2*)(&Pt[prow + c * 16 + quad * 4]) = pp;
      }
      // P frags (same-wave rows; in-order LDS pipe, fine-grained lgkmcnt)
      bf16x8 pf0 = *(const bf16x8*)(&Pt[prow + quad * 8]);
      bf16x8 pf1 = *(const bf16x8*)(&Pt[prow + 32 + quad * 8]);
      // l += P . 1  (C-layout, same rows as O)
      lacc[g] = __builtin_amdgcn_mfma_f32_16x16x32_bf16(pf0, ones, lacc[g], 0, 0, 0);
      lacc[g] = __builtin_amdgcn_mfma_f32_16x16x32_bf16(pf1, ones, lacc[g], 0, 0, 0);
      // O += P . V
#pragma unroll
      for (int c = 0; c < 4; ++c) {
        o[g][c] = __builtin_amdgcn_mfma_f32_16x16x32_bf16(pf0, vb[c][0], o[g][c], 0, 0, 0);
        o[g][c] = __builtin_amdgcn_mfma_f32_16x16x32_bf16(pf1, vb[c][1], o[g][c], 0, 0, 0);
      }
    }
  }

  // partial store: unnormalized O (bf16) + l (fp32), row = bh*SEQ + t
#pragma unroll
  for (int g = 0; g < 2; ++g) {
#pragma unroll
    for (int c = 0; c < 4; ++c)
#pragma unroll
      for (int r = 0; r < 4; ++r) {
        int t = q0 + wave * 32 + g * 16 + quad * 4 + r;
        Op[((size_t)bh * SEQ + t) * 64 + c * 16 + l16] = f2b(o[g][c][r]);
      }
    if (l16 == 0) {
#pragma unroll
      for (int r = 0; r < 4; ++r) {
        int t = q0 + wave * 32 + g * 16 + quad * 4 + r;
        lp[(size_t)bh * SEQ + t] = lacc[g][r];
      }
    }
  }
}

// ctx = (O1 + O2) / (l1 + l2), routed to (B, T, D_MODEL) bf16
__global__ __launch_bounds__(256) void recombine(const ushort* __restrict__ O1,
                                                 const ushort* __restrict__ O2,
                                                 const float* __restrict__ l1,
                                                 const float* __restrict__ l2,
                                                 ushort* __restrict__ ctx) {
  int idx = blockIdx.x * 256 + threadIdx.x;   // over (BH*T*64)/8 uint4 chunks
  int row = idx >> 3;                         // bh*SEQ + t
  int d8 = idx & 7;
  uint4 a = ((const uint4*)O1)[idx];
  uint4 b = ((const uint4*)O2)[idx];
  float linv = 1.f / (l1[row] + l2[row]);
  uint4 res;
  unsigned* ap = (unsigned*)&a;
  unsigned* bp = (unsigned*)&b;
  unsigned* rp = (unsigned*)&res;
#pragma unroll
  for (int i = 0; i < 4; ++i) {
    float lo = (blo(ap[i]) + blo(bp[i])) * linv;
    float hi = (bhi(ap[i]) + bhi(bp[i])) * linv;
    rp[i] = pk2(lo, hi);
  }
  int bh = row >> 11, t = row & 2047;
  int bb = bh >> 4, h = bh & 15;
  ((uint4*)ctx)[(size_t)(bb * SEQ + t) * 128 + h * 8 + d8] = res;
}

extern "C" void kernel_launch(void* const* d_in, const int* in_sizes, int n_in,
                              void* d_out, int out_size, void* d_ws, size_t ws_size,
                              hipStream_t stream) {
  const float* x  = (const float*)d_in[0];
  const float* Wq = (const float*)d_in[1];
  const float* Wk = (const float*)d_in[2];
  const float* Wv = (const float*)d_in[3];
  const float* Wo = (const float*)d_in[4];
  float* out = (float*)d_out;

  char* ws = (char*)d_ws;
  const size_t MB = 1 << 20;
  ushort* xb   = (ushort*)(ws);             // 8 MB (dead after gemm_qkv -> O2)
  ushort* wqkv = (ushort*)(ws +  8 * MB);   // 6 MB (dead after gemm_qkv -> l1/l2)
  ushort* wob  = (ushort*)(ws + 14 * MB);   // 2 MB (live until gemm_out)
  ushort* Qh   = (ushort*)(ws + 16 * MB);   // 8 MB (BH,T,64)
  ushort* Kh   = (ushort*)(ws + 24 * MB);   // 8 MB (BH,T,64)
  ushort* Vth  = (ushort*)(ws + 32 * MB);   // 8 MB (BH,64,T)
  ushort* ctx  = (ushort*)(ws + 40 * MB);   // 8 MB (B,T,D)

  // split-K partials (regions dead during attn):
  ushort* O1 = (ushort*)d_out;              // 8 MB of the 16 MB output buffer
  ushort* O2 = xb;                          // xb region, dead after gemm_qkv
  float*  l1 = (float*)wqkv;                // 256 KB
  float*  l2 = (float*)(ws + 8 * MB + 256 * 1024);

  cast_all<<<8192, 256, 0, stream>>>(x, Wq, Wk, Wv, Wo, xb, wqkv, wob);

  const float qscale = 0.125f * 1.44269504089f;  // SCALE * log2(e)
  gemm_qkv<<<dim3(3072 / 128, 4096 / 128), 256, 0, stream>>>(xb, wqkv, Qh, Kh, Vth, qscale);

  attn_kernel<<<dim3(SEQ / 128, BATCH * N_HEADS, 2), 256, 0, stream>>>(
      Qh, Kh, Vth, O1, O2, l1, l2);

  recombine<<<(BATCH * N_HEADS * SEQ * 64 / 8) / 256, 256, 0, stream>>>(O1, O2, l1, l2, ctx);

  gemm_out<<<dim3(1024 / 128, 4096 / 64), 256, 0, stream>>>(ctx, wob, out);
}

// Round 11
// 215.663 us; speedup vs baseline: 1.1270x; 1.1270x over previous
//
#include <hip/hip_runtime.h>
#include <hip/hip_bf16.h>

#define D_MODEL 1024
#define N_HEADS 16
#define HEAD_DIM 64
#define SEQ 2048
#define BATCH 2

typedef __attribute__((ext_vector_type(8))) short bf16x8;
typedef __attribute__((ext_vector_type(4))) float f32x4;

typedef __attribute__((address_space(3))) unsigned lds_uint;
typedef __attribute__((address_space(1))) const unsigned global_cuint;

__device__ __forceinline__ void async_cp16(const ushort* g, ushort* l) {
  __builtin_amdgcn_global_load_lds((global_cuint*)g, (lds_uint*)l, 16, 0, 0);
}

__device__ __forceinline__ ushort f2b(float f) {
  union { float f; unsigned u; } x; x.f = f;
  unsigned r = x.u + 0x7fffu + ((x.u >> 16) & 1u);
  return (ushort)(r >> 16);
}

// packed f32x2 -> bf16x2; low word = a
__device__ __forceinline__ unsigned pk2(float a, float b) {
  __hip_bfloat162 h = __float22bfloat162_rn(float2{a, b});
  union { __hip_bfloat162 h; unsigned u; } x; x.h = h;
  return x.u;
}

__device__ __forceinline__ float blo(unsigned u) {
  union { unsigned u; float f; } x; x.u = u << 16; return x.f;
}
__device__ __forceinline__ float bhi(unsigned u) {
  union { unsigned u; float f; } x; x.u = u & 0xffff0000u; return x.f;
}

// Single fused cast: x (1M uint4) + Wq/Wk/Wv (-> wqkv) + Wo (-> wob).
__global__ __launch_bounds__(256) void cast_all(const float* __restrict__ x,
                                                const float* __restrict__ Wq,
                                                const float* __restrict__ Wk,
                                                const float* __restrict__ Wv,
                                                const float* __restrict__ Wo,
                                                ushort* __restrict__ xb,
                                                ushort* __restrict__ wqkv,
                                                ushort* __restrict__ wob) {
  int idx = blockIdx.x * 256 + threadIdx.x;  // 0 .. 2M-1 (uint4 units)
  const float* in;
  uint2* out;
  if (idx < (1 << 20)) {
    in = x; out = (uint2*)xb;
  } else {
    int j = idx - (1 << 20);
    int w = j >> 18;            // 0..3
    idx = j & 0x3FFFF;          // 256K uint4 per weight
    switch (w) {
      case 0: in = Wq; out = (uint2*)wqkv; break;
      case 1: in = Wk; out = (uint2*)(wqkv) + (1 << 18); break;
      case 2: in = Wv; out = (uint2*)(wqkv) + (2 << 18); break;
      default: in = Wo; out = (uint2*)wob; break;
    }
  }
  float4 v = ((const float4*)in)[idx];
  uint2 o; o.x = pk2(v.x, v.y); o.y = pk2(v.z, v.w);
  out[idx] = o;
}

// Fused QKV projection: A = xb (4096x1024 bf16), Bw = wqkv (3072x1024 bf16).
// 128x128 tile, BK=64 (16 K-iters).
// n<1024 -> Q (scaled), <2048 -> K, else -> V^T (packed b64 stores along t).
__global__ __launch_bounds__(256) void gemm_qkv(const ushort* __restrict__ A,
                                                const ushort* __restrict__ Bw,
                                                ushort* __restrict__ Qh,
                                                ushort* __restrict__ Kh,
                                                ushort* __restrict__ Vth,
                                                float qscale) {
  constexpr int K = 1024;
  const int bm = blockIdx.y * 128;
  const int bn = blockIdx.x * 128;
  const int tid = threadIdx.x;
  const int wave = tid >> 6;
  const int lane = tid & 63;
  const int l16 = lane & 15;
  const int quad = lane >> 4;

  __shared__ ushort As[128 * 64];   // 16 KB
  __shared__ ushort Bs[128 * 64];   // 16 KB

  const int wm = (wave & 1) * 64;
  const int wn = (wave >> 1) * 64;

  f32x4 acc[4][4];
#pragma unroll
  for (int r = 0; r < 4; ++r)
#pragma unroll
    for (int c = 0; c < 4; ++c) acc[r][c] = (f32x4){0.f, 0.f, 0.f, 0.f};

  const int srow = wave * 8 + (lane >> 3);
  const int scol = (lane & 7) * 8;

  for (int k0 = 0; k0 < K; k0 += 64) {
#pragma unroll
    for (int j = 0; j < 4; ++j) {
      async_cp16(A  + (size_t)(bm + j * 32 + srow) * K + k0 + scol, &As[(j * 32 + wave * 8) * 64]);
      async_cp16(Bw + (size_t)(bn + j * 32 + srow) * K + k0 + scol, &Bs[(j * 32 + wave * 8) * 64]);
    }
    __syncthreads();

    bf16x8 a[2][4], b[2][4];
#pragma unroll
    for (int ks = 0; ks < 2; ++ks)
#pragma unroll
      for (int r = 0; r < 4; ++r) {
        a[ks][r] = *(const bf16x8*)(&As[(wm + r * 16 + l16) * 64 + ks * 32 + quad * 8]);
        b[ks][r] = *(const bf16x8*)(&Bs[(wn + r * 16 + l16) * 64 + ks * 32 + quad * 8]);
      }
#pragma unroll
    for (int ks = 0; ks < 2; ++ks)
#pragma unroll
      for (int r = 0; r < 4; ++r)
#pragma unroll
        for (int c = 0; c < 4; ++c)
          acc[r][c] = __builtin_amdgcn_mfma_f32_16x16x32_bf16(a[ks][r], b[ks][c], acc[r][c], 0, 0, 0);
    __syncthreads();
  }

#pragma unroll
  for (int r = 0; r < 4; ++r) {
#pragma unroll
    for (int c = 0; c < 4; ++c) {
      int ncol = bn + wn + c * 16 + l16;   // 0..3071; w uniform per (block,wave)
      int w = ncol >> 10;
      int f = ncol & 1023;
      int h = f >> 6, d = f & 63;
      if (w == 2) {
        // V^T: 4 consecutive tokens per lane -> one b64 store
        int m0 = bm + wm + r * 16 + quad * 4;
        int b = m0 >> 11, t0 = m0 & 2047;
        uint2 pp;
        pp.x = pk2(acc[r][c][0], acc[r][c][1]);
        pp.y = pk2(acc[r][c][2], acc[r][c][3]);
        *(uint2*)(&Vth[((size_t)(b * 1024 + f) << 11) + t0]) = pp;
      } else {
#pragma unroll
        for (int rr = 0; rr < 4; ++rr) {
          float v = acc[r][c][rr];
          int m = bm + wm + r * 16 + quad * 4 + rr;
          int b = m >> 11, t = m & 2047;
          if (w == 0)
            Qh[((size_t)(b * 16 + h) * SEQ + t) * 64 + d] = f2b(v * qscale);
          else
            Kh[((size_t)(b * 16 + h) * SEQ + t) * 64 + d] = f2b(v);
        }
      }
    }
  }
}

// Output projection: A = ctx (4096x1024 bf16), Bw = wob, fp32 out.
// 64x128 tile, BK=64.
__global__ __launch_bounds__(256) void gemm_out(const ushort* __restrict__ A,
                                                const ushort* __restrict__ Bw,
                                                float* __restrict__ out) {
  constexpr int K = 1024;
  const int bm = blockIdx.y * 64;
  const int bn = blockIdx.x * 128;
  const int tid = threadIdx.x;
  const int wave = tid >> 6;
  const int lane = tid & 63;
  const int l16 = lane & 15;
  const int quad = lane >> 4;

  __shared__ ushort As[64 * 64];    //  8 KB
  __shared__ ushort Bs[128 * 64];   // 16 KB

  const int wm = (wave & 1) * 32;
  const int wn = (wave >> 1) * 64;

  f32x4 acc[2][4];
#pragma unroll
  for (int r = 0; r < 2; ++r)
#pragma unroll
    for (int c = 0; c < 4; ++c) acc[r][c] = (f32x4){0.f, 0.f, 0.f, 0.f};

  const int srow = wave * 8 + (lane >> 3);
  const int scol = (lane & 7) * 8;

  for (int k0 = 0; k0 < K; k0 += 64) {
#pragma unroll
    for (int j = 0; j < 2; ++j)
      async_cp16(A + (size_t)(bm + j * 32 + srow) * K + k0 + scol, &As[(j * 32 + wave * 8) * 64]);
#pragma unroll
    for (int j = 0; j < 4; ++j)
      async_cp16(Bw + (size_t)(bn + j * 32 + srow) * K + k0 + scol, &Bs[(j * 32 + wave * 8) * 64]);
    __syncthreads();

    bf16x8 a[2][2], b[2][4];
#pragma unroll
    for (int ks = 0; ks < 2; ++ks) {
#pragma unroll
      for (int r = 0; r < 2; ++r)
        a[ks][r] = *(const bf16x8*)(&As[(wm + r * 16 + l16) * 64 + ks * 32 + quad * 8]);
#pragma unroll
      for (int c = 0; c < 4; ++c)
        b[ks][c] = *(const bf16x8*)(&Bs[(wn + c * 16 + l16) * 64 + ks * 32 + quad * 8]);
    }
#pragma unroll
    for (int ks = 0; ks < 2; ++ks)
#pragma unroll
      for (int r = 0; r < 2; ++r)
#pragma unroll
        for (int c = 0; c < 4; ++c)
          acc[r][c] = __builtin_amdgcn_mfma_f32_16x16x32_bf16(a[ks][r], b[ks][c], acc[r][c], 0, 0, 0);
    __syncthreads();
  }

#pragma unroll
  for (int r = 0; r < 2; ++r)
#pragma unroll
    for (int c = 0; c < 4; ++c)
#pragma unroll
      for (int rr = 0; rr < 4; ++rr) {
        int m = bm + wm + r * 16 + quad * 4 + rr;
        int n = bn + wn + c * 16 + l16;
        out[(size_t)m * D_MODEL + n] = acc[r][c][rr];
      }
}

// Flash attention (R8 structure): S^T formulation, fixed-max softmax (exp2
// domain), split-K=2, 64 q-rows per wave. R11: 1D grid with XCD-affinity
// swizzle — id = qb*64 + stream (stream = bh*2+half); 64%8==0 so all 8
// q-blocks of one K/V stream share id%8 -> same XCD -> 8 streams/XCD = 2 MB
// < 4 MB L2. Pure index relabeling of the R8 grid (512 blocks). O-partial
// store reordered r-outer/c-inner so each 128B line is filled by 4
// consecutive stores (closes lines immediately; anti write-amplification).
__global__ __launch_bounds__(256, 2) void attn_kernel(const ushort* __restrict__ Qh,
                                                      const ushort* __restrict__ Kh,
                                                      const ushort* __restrict__ Vth,
                                                      ushort* __restrict__ O1,
                                                      ushort* __restrict__ O2,
                                                      float* __restrict__ l1,
                                                      float* __restrict__ l2) {
  const int id = blockIdx.x;
  const int stream = id & 63;       // bh*2 + half
  const int qb = id >> 6;           // 0..7
  const int bh = stream >> 1;
  const int half = stream & 1;
  const int q0 = qb * 256;
  ushort* __restrict__ Op = half ? O2 : O1;
  float* __restrict__ lp = half ? l2 : l1;

  const int tid = threadIdx.x;
  const int wave = tid >> 6;
  const int lane = tid & 63;
  const int l16 = lane & 15;
  const int quad = lane >> 4;

  __shared__ ushort Kt[64 * 72];    // [key][d]
  __shared__ ushort Vt[64 * 72];    // [d][key]
  __shared__ ushort Pt[256 * 72];   // [q][key] (wave-private rows)

  bf16x8 qf[4][2];
#pragma unroll
  for (int g = 0; g < 4; ++g) {
    const ushort* qp = Qh + ((size_t)bh * SEQ + q0 + wave * 64 + g * 16 + l16) * 64 + quad * 8;
    qf[g][0] = *(const bf16x8*)(qp);
    qf[g][1] = *(const bf16x8*)(qp + 32);
  }

  bf16x8 ones;
#pragma unroll
  for (int j = 0; j < 8; ++j) ones[j] = (short)0x3F80;  // bf16 1.0

  f32x4 o[4][4];
  f32x4 lacc[4];
#pragma unroll
  for (int g = 0; g < 4; ++g) {
    lacc[g] = (f32x4){0.f, 0.f, 0.f, 0.f};
#pragma unroll
    for (int c = 0; c < 4; ++c) o[g][c] = (f32x4){0.f, 0.f, 0.f, 0.f};
  }

  const int srow = tid >> 3;        // 0..31
  const int scol = (tid & 7) * 8;
  const ushort* kbase = Kh + ((size_t)bh * SEQ + half * 1024) * 64;
  const ushort* vbase = Vth + (size_t)bh * 64 * SEQ + half * 1024;

  uint4 kreg[2], vreg[2];
#pragma unroll
  for (int i = 0; i < 2; ++i) {
    kreg[i] = *(const uint4*)(kbase + (size_t)(i * 32 + srow) * 64 + scol);
    vreg[i] = *(const uint4*)(vbase + (size_t)(i * 32 + srow) * SEQ + scol);
  }

  constexpr int NIT = 1024 / 64;  // 16
  for (int kt = 0; kt < NIT; ++kt) {
    __syncthreads();  // prior-iter LDS reads complete
#pragma unroll
    for (int i = 0; i < 2; ++i) {
      *(uint4*)(&Kt[(i * 32 + srow) * 72 + scol]) = kreg[i];
      *(uint4*)(&Vt[(i * 32 + srow) * 72 + scol]) = vreg[i];
    }
    __syncthreads();  // staging visible
    if (kt + 1 < NIT) {
      // issued after the barrier so its vmcnt drain doesn't eat the prefetch
#pragma unroll
      for (int i = 0; i < 2; ++i) {
        kreg[i] = *(const uint4*)(kbase + (size_t)((kt + 1) * 64 + i * 32 + srow) * 64 + scol);
        vreg[i] = *(const uint4*)(vbase + (size_t)(i * 32 + srow) * SEQ + (kt + 1) * 64 + scol);
      }
    }

    // hoisted K frags (A-op: m = key c*16+l16, k = d) and V frags (B-op: n = d)
    bf16x8 ka[4][2], vb[4][2];
#pragma unroll
    for (int c = 0; c < 4; ++c)
#pragma unroll
      for (int ks = 0; ks < 2; ++ks) {
        ka[c][ks] = *(const bf16x8*)(&Kt[(c * 16 + l16) * 72 + ks * 32 + quad * 8]);
        vb[c][ks] = *(const bf16x8*)(&Vt[(c * 16 + l16) * 72 + ks * 32 + quad * 8]);
      }

#pragma unroll
    for (int g = 0; g < 4; ++g) {
      const int prow = (wave * 64 + g * 16 + l16) * 72;
      // S^T per key-chunk: MFMA -> exp2 -> pack -> LDS (no cross-lane ops)
#pragma unroll
      for (int c = 0; c < 4; ++c) {
        f32x4 z = (f32x4){0.f, 0.f, 0.f, 0.f};
        z = __builtin_amdgcn_mfma_f32_16x16x32_bf16(ka[c][0], qf[g][0], z, 0, 0, 0);
        z = __builtin_amdgcn_mfma_f32_16x16x32_bf16(ka[c][1], qf[g][1], z, 0, 0, 0);
        uint2 pp;
        pp.x = pk2(__builtin_amdgcn_exp2f(z[0]), __builtin_amdgcn_exp2f(z[1]));
        pp.y = pk2(__builtin_amdgcn_exp2f(z[2]), __builtin_amdgcn_exp2f(z[3]));
        *(uint2*)(&Pt[prow + c * 16 + quad * 4]) = pp;
      }
      // P frags (same-wave rows; in-order LDS pipe, fine-grained lgkmcnt)
      bf16x8 pf0 = *(const bf16x8*)(&Pt[prow + quad * 8]);
      bf16x8 pf1 = *(const bf16x8*)(&Pt[prow + 32 + quad * 8]);
      // l += P . 1  (C-layout, same rows as O)
      lacc[g] = __builtin_amdgcn_mfma_f32_16x16x32_bf16(pf0, ones, lacc[g], 0, 0, 0);
      lacc[g] = __builtin_amdgcn_mfma_f32_16x16x32_bf16(pf1, ones, lacc[g], 0, 0, 0);
      // O += P . V
#pragma unroll
      for (int c = 0; c < 4; ++c) {
        o[g][c] = __builtin_amdgcn_mfma_f32_16x16x32_bf16(pf0, vb[c][0], o[g][c], 0, 0, 0);
        o[g][c] = __builtin_amdgcn_mfma_f32_16x16x32_bf16(pf1, vb[c][1], o[g][c], 0, 0, 0);
      }
    }
  }

  // partial store: unnormalized O (bf16) + l (fp32), row = bh*SEQ + t.
  // r-outer/c-inner: 4 consecutive stores fill each set of 4 cache lines.
#pragma unroll
  for (int g = 0; g < 4; ++g) {
#pragma unroll
    for (int r = 0; r < 4; ++r) {
      int t = q0 + wave * 64 + g * 16 + quad * 4 + r;
#pragma unroll
      for (int c = 0; c < 4; ++c)
        Op[((size_t)bh * SEQ + t) * 64 + c * 16 + l16] = f2b(o[g][c][r]);
    }
    if (l16 == 0) {
#pragma unroll
      for (int r = 0; r < 4; ++r) {
        int t = q0 + wave * 64 + g * 16 + quad * 4 + r;
        lp[(size_t)bh * SEQ + t] = lacc[g][r];
      }
    }
  }
}

// ctx = (O1 + O2) / (l1 + l2), routed to (B, T, D_MODEL) bf16
__global__ __launch_bounds__(256) void recombine(const ushort* __restrict__ O1,
                                                 const ushort* __restrict__ O2,
                                                 const float* __restrict__ l1,
                                                 const float* __restrict__ l2,
                                                 ushort* __restrict__ ctx) {
  int idx = blockIdx.x * 256 + threadIdx.x;   // over (BH*T*64)/8 uint4 chunks
  int row = idx >> 3;                         // bh*SEQ + t
  int d8 = idx & 7;
  uint4 a = ((const uint4*)O1)[idx];
  uint4 b = ((const uint4*)O2)[idx];
  float linv = 1.f / (l1[row] + l2[row]);
  uint4 res;
  unsigned* ap = (unsigned*)&a;
  unsigned* bp = (unsigned*)&b;
  unsigned* rp = (unsigned*)&res;
#pragma unroll
  for (int i = 0; i < 4; ++i) {
    float lo = (blo(ap[i]) + blo(bp[i])) * linv;
    float hi = (bhi(ap[i]) + bhi(bp[i])) * linv;
    rp[i] = pk2(lo, hi);
  }
  int bh = row >> 11, t = row & 2047;
  int bb = bh >> 4, h = bh & 15;
  ((uint4*)ctx)[(size_t)(bb * SEQ + t) * 128 + h * 8 + d8] = res;
}

extern "C" void kernel_launch(void* const* d_in, const int* in_sizes, int n_in,
                              void* d_out, int out_size, void* d_ws, size_t ws_size,
                              hipStream_t stream) {
  const float* x  = (const float*)d_in[0];
  const float* Wq = (const float*)d_in[1];
  const float* Wk = (const float*)d_in[2];
  const float* Wv = (const float*)d_in[3];
  const float* Wo = (const float*)d_in[4];
  float* out = (float*)d_out;

  char* ws = (char*)d_ws;
  const size_t MB = 1 << 20;
  ushort* xb   = (ushort*)(ws);             // 8 MB (dead after gemm_qkv -> O2)
  ushort* wqkv = (ushort*)(ws +  8 * MB);   // 6 MB (dead after gemm_qkv -> l1/l2)
  ushort* wob  = (ushort*)(ws + 14 * MB);   // 2 MB (live until gemm_out)
  ushort* Qh   = (ushort*)(ws + 16 * MB);   // 8 MB (BH,T,64)
  ushort* Kh   = (ushort*)(ws + 24 * MB);   // 8 MB (BH,T,64)
  ushort* Vth  = (ushort*)(ws + 32 * MB);   // 8 MB (BH,64,T)
  ushort* ctx  = (ushort*)(ws + 40 * MB);   // 8 MB (B,T,D)

  // split-K partials (regions dead during attn):
  ushort* O1 = (ushort*)d_out;              // 8 MB of the 16 MB output buffer
  ushort* O2 = xb;                          // xb region, dead after gemm_qkv
  float*  l1 = (float*)wqkv;                // 256 KB
  float*  l2 = (float*)(ws + 8 * MB + 256 * 1024);

  cast_all<<<8192, 256, 0, stream>>>(x, Wq, Wk, Wv, Wo, xb, wqkv, wob);

  const float qscale = 0.125f * 1.44269504089f;  // SCALE * log2(e)
  gemm_qkv<<<dim3(3072 / 128, 4096 / 128), 256, 0, stream>>>(xb, wqkv, Qh, Kh, Vth, qscale);

  // 1D grid, 512 blocks: id = qb*64 + (bh*2+half) -> id%8 fixed per stream
  attn_kernel<<<(SEQ / 256) * BATCH * N_HEADS * 2, 256, 0, stream>>>(
      Qh, Kh, Vth, O1, O2, l1, l2);

  recombine<<<(BATCH * N_HEADS * SEQ * 64 / 8) / 256, 256, 0, stream>>>(O1, O2, l1, l2, ctx);

  gemm_out<<<dim3(1024 / 128, 4096 / 64), 256, 0, stream>>>(ctx, wob, out);
}